// Round 1
// baseline (72.970 us; speedup 1.0000x reference)
//
#include <hip/hip_runtime.h>

#define WIN   9
#define PAD   4
#define TILE_W 64
#define TILE_H 16
#define IMG_H 512
#define IMG_W 512
#define NBATCH 16
#define NPIX  (16.0 * 512.0 * 512.0)
#define EPS   1e-5f

// One block computes a TILE_H x TILE_W output tile of one image.
// Phase 1: load (TILE_H+8) x (TILE_W+8) input halo tile of I and J into LDS.
// Phase 2: vertical 9-sums of {I, J, I^2, J^2, I*J} -> LDS column-sum arrays.
// Phase 3: horizontal 9-sums per output pixel, per-pixel cc, local accumulate.
// Phase 4: block reduction, one double atomicAdd per block into d_ws.
__global__ __launch_bounds__(256) void ncc_tile_kernel(
    const float* __restrict__ I, const float* __restrict__ J,
    double* __restrict__ acc)
{
    __shared__ float sI [TILE_H + 8][TILE_W + 8];
    __shared__ float sJ [TILE_H + 8][TILE_W + 8];
    __shared__ float cI [TILE_H][TILE_W + 8];
    __shared__ float cJ [TILE_H][TILE_W + 8];
    __shared__ float cII[TILE_H][TILE_W + 8];
    __shared__ float cJJ[TILE_H][TILE_W + 8];
    __shared__ float cIJ[TILE_H][TILE_W + 8];

    const int tid = threadIdx.x;
    const int bx  = blockIdx.x * TILE_W;
    const int by  = blockIdx.y * TILE_H;
    const int b   = blockIdx.z;
    const size_t base = (size_t)b * IMG_H * IMG_W;

    // ---- Phase 1: load with zero padding outside the image ----
    for (int i = tid; i < (TILE_H + 8) * (TILE_W + 8); i += 256) {
        int r = i / (TILE_W + 8);
        int c = i - r * (TILE_W + 8);
        int gy = by + r - PAD;
        int gx = bx + c - PAD;
        float vi = 0.0f, vj = 0.0f;
        if (gy >= 0 && gy < IMG_H && gx >= 0 && gx < IMG_W) {
            size_t idx = base + (size_t)gy * IMG_W + gx;
            vi = I[idx];
            vj = J[idx];
        }
        sI[r][c] = vi;
        sJ[r][c] = vj;
    }
    __syncthreads();

    // ---- Phase 2: vertical 9-sums of the five quantities ----
    for (int i = tid; i < TILE_H * (TILE_W + 8); i += 256) {
        int r = i / (TILE_W + 8);
        int c = i - r * (TILE_W + 8);
        float si = 0.f, sj = 0.f, sii = 0.f, sjj = 0.f, sij = 0.f;
        #pragma unroll
        for (int dy = 0; dy < WIN; ++dy) {
            float a  = sI[r + dy][c];
            float bv = sJ[r + dy][c];
            si  += a;
            sj  += bv;
            sii += a * a;
            sjj += bv * bv;
            sij += a * bv;
        }
        cI [r][c] = si;
        cJ [r][c] = sj;
        cII[r][c] = sii;
        cJJ[r][c] = sjj;
        cIJ[r][c] = sij;
    }
    __syncthreads();

    // ---- Phase 3: horizontal 9-sums + per-pixel cc ----
    float local = 0.0f;
    for (int i = tid; i < TILE_H * TILE_W; i += 256) {
        int r = i >> 6;        // /64
        int c = i & 63;        // %64
        float Is = 0.f, Js = 0.f, IIs = 0.f, JJs = 0.f, IJs = 0.f;
        #pragma unroll
        for (int dx = 0; dx < WIN; ++dx) {
            Is  += cI [r][c + dx];
            Js  += cJ [r][c + dx];
            IIs += cII[r][c + dx];
            JJs += cJJ[r][c + dx];
            IJs += cIJ[r][c + dx];
        }
        const float wsz = 81.0f;
        float uI = Is / wsz;
        float uJ = Js / wsz;
        float cross = IJs - uJ * Is - uI * Js + uI * uJ * wsz;
        cross = fmaxf(cross, EPS);
        float Ivar = IIs - 2.0f * uI * Is + uI * uI * wsz;
        Ivar = fmaxf(Ivar, EPS);
        float Jvar = JJs - 2.0f * uJ * Js + uJ * uJ * wsz;
        Jvar = fmaxf(Jvar, EPS);
        local += (cross * cross) / (Ivar * Jvar);
    }

    // ---- Phase 4: block reduction, one atomic per block ----
    #pragma unroll
    for (int off = 32; off > 0; off >>= 1)
        local += __shfl_down(local, off, 64);

    __shared__ float wsum[4];
    int wid  = tid >> 6;
    int lane = tid & 63;
    if (lane == 0) wsum[wid] = local;
    __syncthreads();
    if (tid == 0) {
        double t = ((double)wsum[0] + (double)wsum[1]) +
                   ((double)wsum[2] + (double)wsum[3]);
        atomicAdd(acc, t);
    }
}

__global__ void ncc_finalize_kernel(const double* __restrict__ acc,
                                    float* __restrict__ out)
{
    out[0] = (float)(-acc[0] / NPIX);
}

extern "C" void kernel_launch(void* const* d_in, const int* in_sizes, int n_in,
                              void* d_out, int out_size, void* d_ws, size_t ws_size,
                              hipStream_t stream)
{
    const float* I = (const float*)d_in[0];   // y_true
    const float* J = (const float*)d_in[1];   // y_pred
    float* out = (float*)d_out;
    double* acc = (double*)d_ws;

    hipMemsetAsync(acc, 0, sizeof(double), stream);

    dim3 grid(IMG_W / TILE_W, IMG_H / TILE_H, NBATCH);
    ncc_tile_kernel<<<grid, 256, 0, stream>>>(I, J, acc);
    ncc_finalize_kernel<<<1, 1, 0, stream>>>(acc, out);
}